// Round 9
// baseline (37.658 us; speedup 1.0000x reference)
//
#include <hip/hip_runtime.h>
#include <math.h>

#define NB  2048   // total blocks: every block = stream slice + pair slice
#define TPB 256

__device__ __forceinline__ float waveReduceSum(float v) {
    #pragma unroll
    for (int off = 32; off > 0; off >>= 1)
        v += __shfl_down(v, off, 64);
    return v;
}

// ws layout (floats): [0,NB) s0 partials ; [NB,2NB) s1 partials ; [2NB,3NB) pair partials
__global__ __launch_bounds__(TPB, 8)
void fused_kernel(const float* __restrict__ a,
                  const float* __restrict__ p,
                  const float* __restrict__ Pm,
                  const float* __restrict__ S,
                  const int* __restrict__ ii,
                  const int* __restrict__ jj,
                  float* __restrict__ ws,
                  long nAP, long nP, int Npair, int D, int K)
{
    __shared__ float sm0[4], sm1[4], sm2[4];
    const int wave = threadIdx.x >> 6;
    const int lane = threadIdx.x & 63;
    const int bid  = blockIdx.x;

    // ---------------- stream slice (R2/R8-proven 4-wide named batches) ----------------
    const long tid    = (long)bid * TPB + threadIdx.x;
    const long stride = (long)NB * TPB;               // 524,288 threads

    const float4* a4 = (const float4*)a;
    const float4* p4 = (const float4*)p;
    const long n4 = nAP >> 2;                         // 4,194,304 -> exactly 8/thread

    float s0a = 0.f, s0b = 0.f, s0c = 0.f, s0d = 0.f;
    long i = tid;
    for (; i + 3 * stride < n4; i += 4 * stride) {    // exactly 2 iterations
        float4 av0 = a4[i];
        float4 av1 = a4[i + stride];
        float4 av2 = a4[i + 2 * stride];
        float4 av3 = a4[i + 3 * stride];
        float4 pv0 = p4[i];
        float4 pv1 = p4[i + stride];
        float4 pv2 = p4[i + 2 * stride];
        float4 pv3 = p4[i + 3 * stride];
        float d;
        d = av0.x - pv0.x; s0a += d * d;
        d = av0.y - pv0.y; s0a += d * d;
        d = av0.z - pv0.z; s0a += d * d;
        d = av0.w - pv0.w; s0a += d * d;
        d = av1.x - pv1.x; s0b += d * d;
        d = av1.y - pv1.y; s0b += d * d;
        d = av1.z - pv1.z; s0b += d * d;
        d = av1.w - pv1.w; s0b += d * d;
        d = av2.x - pv2.x; s0c += d * d;
        d = av2.y - pv2.y; s0c += d * d;
        d = av2.z - pv2.z; s0c += d * d;
        d = av2.w - pv2.w; s0c += d * d;
        d = av3.x - pv3.x; s0d += d * d;
        d = av3.y - pv3.y; s0d += d * d;
        d = av3.z - pv3.z; s0d += d * d;
        d = av3.w - pv3.w; s0d += d * d;
    }
    for (; i < n4; i += stride) {                     // zero iterations at this shape
        float4 av = a4[i], pv = p4[i];
        float d;
        d = av.x - pv.x; s0a += d * d;
        d = av.y - pv.y; s0a += d * d;
        d = av.z - pv.z; s0a += d * d;
        d = av.w - pv.w; s0a += d * d;
    }

    const float4* P4 = (const float4*)Pm;
    const long nP4 = nP >> 2;                         // 1,048,576 -> exactly 2/thread
    float s1a = 0.f, s1b = 0.f;
    i = tid;
    for (; i + stride < nP4; i += 2 * stride) {       // exactly 1 iteration
        float4 v0 = P4[i];
        float4 v1 = P4[i + stride];
        float r;
        r = fmaxf(v0.x, 0.f); s1a += r * r;
        r = fmaxf(v0.y, 0.f); s1a += r * r;
        r = fmaxf(v0.z, 0.f); s1a += r * r;
        r = fmaxf(v0.w, 0.f); s1a += r * r;
        r = fmaxf(v1.x, 0.f); s1b += r * r;
        r = fmaxf(v1.y, 0.f); s1b += r * r;
        r = fmaxf(v1.z, 0.f); s1b += r * r;
        r = fmaxf(v1.w, 0.f); s1b += r * r;
    }
    for (; i < nP4; i += stride) {                    // zero iterations at this shape
        float4 v = P4[i];
        float r;
        r = fmaxf(v.x, 0.f); s1a += r * r;
        r = fmaxf(v.y, 0.f); s1a += r * r;
        r = fmaxf(v.z, 0.f); s1a += r * r;
        r = fmaxf(v.w, 0.f); s1a += r * r;
    }

    float s0 = waveReduceSum(s0a + s0b + s0c + s0d);
    float s1 = waveReduceSum(s1a + s1b);
    if (lane == 0) { sm0[wave] = s0; sm1[wave] = s1; }

    // ---------------- pair slice: 2 pairs per wave, Si hoisted ----------------
    const long totalPairs = (long)Npair * Npair;      // 16,384
    const long base = ((long)bid * 4 + wave) * 2;
    float local = 0.f;

    if (base < totalPairs && D == 1024 && (Npair % 2) == 0) {
        const int ig = (int)(base / Npair);
        const int j0 = (int)(base - (long)ig * Npair);
        const int ri = ii[ig];
        const float4* Si4 = (const float4*)(S + (long)ri * D);
        float4 x0 = Si4[lane];
        float4 x1 = Si4[lane + 64];
        float4 x2 = Si4[lane + 128];
        float4 x3 = Si4[lane + 192];
        const long riK = (long)ri * K;

        float d2q[2];
        int   rjq[2];
        #pragma unroll
        for (int q = 0; q < 2; ++q) {
            const int rj = jj[j0 + q];
            rjq[q] = rj;
            const float4* Sj4 = (const float4*)(S + (long)rj * D);
            float4 y0 = Sj4[lane];
            float4 y1 = Sj4[lane + 64];
            float4 y2 = Sj4[lane + 128];
            float4 y3 = Sj4[lane + 192];
            float d2 = 0.f, e;
            e = x0.x - y0.x; d2 += e * e;
            e = x0.y - y0.y; d2 += e * e;
            e = x0.z - y0.z; d2 += e * e;
            e = x0.w - y0.w; d2 += e * e;
            e = x1.x - y1.x; d2 += e * e;
            e = x1.y - y1.y; d2 += e * e;
            e = x1.z - y1.z; d2 += e * e;
            e = x1.w - y1.w; d2 += e * e;
            e = x2.x - y2.x; d2 += e * e;
            e = x2.y - y2.y; d2 += e * e;
            e = x2.z - y2.z; d2 += e * e;
            e = x2.w - y2.w; d2 += e * e;
            e = x3.x - y3.x; d2 += e * e;
            e = x3.y - y3.y; d2 += e * e;
            e = x3.z - y3.z; d2 += e * e;
            e = x3.w - y3.w; d2 += e * e;
            d2q[q] = d2;
        }
        d2q[0] = waveReduceSum(d2q[0]);
        d2q[1] = waveReduceSum(d2q[1]);
        if (lane == 0) {
            if (d2q[0] > 0.f) local += fmaxf(Pm[riK + rjq[0]], 0.f) * sqrtf(d2q[0]);
            if (d2q[1] > 0.f) local += fmaxf(Pm[riK + rjq[1]], 0.f) * sqrtf(d2q[1]);
        }
    } else {
        // generic fallback for other shapes
        for (long pr = base; pr < base + 2 && pr < totalPairs; ++pr) {
            int ig = (int)(pr / Npair);
            int j  = (int)(pr - (long)ig * Npair);
            int ri = ii[ig];
            int rj = jj[j];
            const float* Si = S + (long)ri * D;
            const float* Sj = S + (long)rj * D;
            float d2 = 0.f;
            for (int c = lane; c < D; c += 64) {
                float e = Si[c] - Sj[c];
                d2 += e * e;
            }
            d2 = waveReduceSum(d2);
            if (lane == 0 && d2 > 0.f)
                local += fmaxf(Pm[(long)ri * K + rj], 0.f) * sqrtf(d2);
        }
    }
    if (lane == 0) sm2[wave] = local;
    __syncthreads();
    if (threadIdx.x == 0) {
        ws[bid]          = sm0[0] + sm0[1] + sm0[2] + sm0[3];
        ws[NB + bid]     = sm1[0] + sm1[1] + sm1[2] + sm1[3];
        ws[2 * NB + bid] = sm2[0] + sm2[1] + sm2[2] + sm2[3];
    }
}

__global__ void finalize_kernel(const float* __restrict__ ws,
                                const float* __restrict__ lamb,
                                float* __restrict__ out)
{
    float a0 = 0.f, a1 = 0.f, a2 = 0.f;
    const float4* w4 = (const float4*)ws;
    for (int i = threadIdx.x; i < NB / 4; i += TPB) {   // 512 float4 per section
        float4 v = w4[i];
        a0 += v.x + v.y + v.z + v.w;
        float4 u = w4[NB / 4 + i];
        a1 += u.x + u.y + u.z + u.w;
        float4 t = w4[2 * (NB / 4) + i];
        a2 += t.x + t.y + t.z + t.w;
    }

    a0 = waveReduceSum(a0);
    a1 = waveReduceSum(a1);
    a2 = waveReduceSum(a2);

    __shared__ float m0[4], m1[4], m2[4];
    int wave = threadIdx.x >> 6;
    int lane = threadIdx.x & 63;
    if (lane == 0) { m0[wave] = a0; m1[wave] = a1; m2[wave] = a2; }
    __syncthreads();
    if (threadIdx.x == 0) {
        float A0 = m0[0] + m0[1] + m0[2] + m0[3];
        float A1 = m1[0] + m1[1] + m1[2] + m1[3];
        float A2 = m2[0] + m2[1] + m2[2] + m2[3];
        out[0] = sqrtf(A0) + lamb[0] * (sqrtf(A1) + A2);
    }
}

extern "C" void kernel_launch(void* const* d_in, const int* in_sizes, int n_in,
                              void* d_out, int out_size, void* d_ws, size_t ws_size,
                              hipStream_t stream) {
    const float* actual = (const float*)d_in[0];
    const float* pred   = (const float*)d_in[1];
    const float* lamb   = (const float*)d_in[2];
    const float* Pm     = (const float*)d_in[3];
    const float* S      = (const float*)d_in[4];
    const int*   ii     = (const int*)d_in[5];
    const int*   jj     = (const int*)d_in[6];
    float* out = (float*)d_out;
    float* ws  = (float*)d_ws;

    long nAP   = in_sizes[0];                       // 4096*4096
    long nP    = in_sizes[3];                       // 2048*2048
    int  K     = (int)lround(sqrt((double)nP));     // 2048
    int  Npair = in_sizes[5];                       // 128
    int  D     = (int)(in_sizes[4] / K);            // 1024

    fused_kernel<<<NB, TPB, 0, stream>>>(actual, pred, Pm, S, ii, jj, ws,
                                         nAP, nP, Npair, D, K);
    finalize_kernel<<<1, TPB, 0, stream>>>(ws, lamb, out);
}

// Round 10
// 35.788 us; speedup vs baseline: 1.0522x; 1.0522x over previous
//
#include <hip/hip_runtime.h>
#include <math.h>

#define BR 1024   // reducer blocks
#define BP 1024   // pair blocks
#define TPB 256

__device__ __forceinline__ float waveReduceSum(float v) {
    #pragma unroll
    for (int off = 32; off > 0; off >>= 1)
        v += __shfl_down(v, off, 64);
    return v;
}

// Fused kernel.
// blocks [0, BP):      parameter_penalty pairs -> ws[2*BR + b]
// blocks [BP, BP+BR):  sum((a-p)^2) -> ws[rb], sum(relu(P)^2) -> ws[BR + rb]
__global__ __launch_bounds__(256, 8)
void fused_kernel(const float* __restrict__ a,
                  const float* __restrict__ p,
                  const float* __restrict__ Pm,
                  const float* __restrict__ S,
                  const int* __restrict__ ii,
                  const int* __restrict__ jj,
                  float* __restrict__ ws,
                  long nAP, long nP, int Npair, int D, int K)
{
    __shared__ float sm0[4], sm1[4];
    const int wave = threadIdx.x >> 6;
    const int lane = threadIdx.x & 63;
    const int bid  = blockIdx.x;

    if (bid < BP) {
        // ---- pair role: VERBATIM R8 (16 pairs/block, 4/wave, Si hoisted) ----
        const int totalPairs = Npair * Npair;
        const int base = bid * 16 + wave * 4;
        float local = 0.f;

        if (base < totalPairs && D == 1024 && (base % Npair) + 3 < Npair) {
            const int i  = base / Npair;
            const int j0 = base - i * Npair;
            const int ri = ii[i];
            const float4* Si4 = (const float4*)(S + (long)ri * D);
            float4 x0 = Si4[lane];
            float4 x1 = Si4[lane + 64];
            float4 x2 = Si4[lane + 128];
            float4 x3 = Si4[lane + 192];
            const long riK = (long)ri * K;

            float d2q[4];
            int   rjq[4];
            #pragma unroll
            for (int q = 0; q < 4; ++q) {
                const int rj = jj[j0 + q];
                rjq[q] = rj;
                const float4* Sj4 = (const float4*)(S + (long)rj * D);
                float4 y0 = Sj4[lane];
                float4 y1 = Sj4[lane + 64];
                float4 y2 = Sj4[lane + 128];
                float4 y3 = Sj4[lane + 192];
                float d2 = 0.f, e;
                e = x0.x - y0.x; d2 += e * e;
                e = x0.y - y0.y; d2 += e * e;
                e = x0.z - y0.z; d2 += e * e;
                e = x0.w - y0.w; d2 += e * e;
                e = x1.x - y1.x; d2 += e * e;
                e = x1.y - y1.y; d2 += e * e;
                e = x1.z - y1.z; d2 += e * e;
                e = x1.w - y1.w; d2 += e * e;
                e = x2.x - y2.x; d2 += e * e;
                e = x2.y - y2.y; d2 += e * e;
                e = x2.z - y2.z; d2 += e * e;
                e = x2.w - y2.w; d2 += e * e;
                e = x3.x - y3.x; d2 += e * e;
                e = x3.y - y3.y; d2 += e * e;
                e = x3.z - y3.z; d2 += e * e;
                e = x3.w - y3.w; d2 += e * e;
                d2q[q] = d2;
            }
            #pragma unroll
            for (int q = 0; q < 4; ++q)
                d2q[q] = waveReduceSum(d2q[q]);
            if (lane == 0) {
                #pragma unroll
                for (int q = 0; q < 4; ++q)
                    if (d2q[q] > 0.f)
                        local += fmaxf(Pm[riK + rjq[q]], 0.f) * sqrtf(d2q[q]);
            }
        } else {
            // generic fallback
            #pragma unroll
            for (int q = 0; q < 4; ++q) {
                int pair = base + q;
                if (pair < totalPairs) {
                    int i = pair / Npair;
                    int j = pair - i * Npair;
                    int ri = ii[i];
                    int rj = jj[j];
                    const float* Si = S + (long)ri * D;
                    const float* Sj = S + (long)rj * D;
                    float d2 = 0.f;
                    for (int c = lane; c < D; c += 64) {
                        float e = Si[c] - Sj[c];
                        d2 += e * e;
                    }
                    d2 = waveReduceSum(d2);
                    if (lane == 0 && d2 > 0.f)
                        local += fmaxf(Pm[(long)ri * K + rj], 0.f) * sqrtf(d2);
                }
            }
        }
        if (lane == 0) sm0[wave] = local;
        __syncthreads();
        if (threadIdx.x == 0)
            ws[2 * BR + bid] = sm0[0] + sm0[1] + sm0[2] + sm0[3];
    } else {
        // ---- reducer role: R2/R8 loop + sched_barrier-forced 8-deep issue ----
        const int rb = bid - BP;
        const long tid    = (long)rb * TPB + threadIdx.x;
        const long stride = (long)BR * TPB;

        const float4* a4 = (const float4*)a;
        const float4* p4 = (const float4*)p;
        long n4 = nAP >> 2;

        float s0a = 0.f, s0b = 0.f, s0c = 0.f, s0d = 0.f;
        long i = tid;
        for (; i + 3 * stride < n4; i += 4 * stride) {
            float4 av0 = a4[i];
            float4 av1 = a4[i + stride];
            float4 av2 = a4[i + 2 * stride];
            float4 av3 = a4[i + 3 * stride];
            float4 pv0 = p4[i];
            float4 pv1 = p4[i + stride];
            float4 pv2 = p4[i + 2 * stride];
            float4 pv3 = p4[i + 3 * stride];
            // force: all 8 loads issue before any consumption is scheduled
            __builtin_amdgcn_sched_barrier(0);
            float d;
            d = av0.x - pv0.x; s0a += d * d;
            d = av0.y - pv0.y; s0a += d * d;
            d = av0.z - pv0.z; s0a += d * d;
            d = av0.w - pv0.w; s0a += d * d;
            d = av1.x - pv1.x; s0b += d * d;
            d = av1.y - pv1.y; s0b += d * d;
            d = av1.z - pv1.z; s0b += d * d;
            d = av1.w - pv1.w; s0b += d * d;
            d = av2.x - pv2.x; s0c += d * d;
            d = av2.y - pv2.y; s0c += d * d;
            d = av2.z - pv2.z; s0c += d * d;
            d = av2.w - pv2.w; s0c += d * d;
            d = av3.x - pv3.x; s0d += d * d;
            d = av3.y - pv3.y; s0d += d * d;
            d = av3.z - pv3.z; s0d += d * d;
            d = av3.w - pv3.w; s0d += d * d;
        }
        for (; i < n4; i += stride) {
            float4 av = a4[i], pv = p4[i];
            float d;
            d = av.x - pv.x; s0a += d * d;
            d = av.y - pv.y; s0a += d * d;
            d = av.z - pv.z; s0a += d * d;
            d = av.w - pv.w; s0a += d * d;
        }

        const float4* P4 = (const float4*)Pm;
        long nP4 = nP >> 2;
        float s1a = 0.f, s1b = 0.f;
        i = tid;
        for (; i + stride < nP4; i += 2 * stride) {
            float4 v0 = P4[i];
            float4 v1 = P4[i + stride];
            __builtin_amdgcn_sched_barrier(0);
            float r;
            r = fmaxf(v0.x, 0.f); s1a += r * r;
            r = fmaxf(v0.y, 0.f); s1a += r * r;
            r = fmaxf(v0.z, 0.f); s1a += r * r;
            r = fmaxf(v0.w, 0.f); s1a += r * r;
            r = fmaxf(v1.x, 0.f); s1b += r * r;
            r = fmaxf(v1.y, 0.f); s1b += r * r;
            r = fmaxf(v1.z, 0.f); s1b += r * r;
            r = fmaxf(v1.w, 0.f); s1b += r * r;
        }
        for (; i < nP4; i += stride) {
            float4 v = P4[i];
            float r;
            r = fmaxf(v.x, 0.f); s1a += r * r;
            r = fmaxf(v.y, 0.f); s1a += r * r;
            r = fmaxf(v.z, 0.f); s1a += r * r;
            r = fmaxf(v.w, 0.f); s1a += r * r;
        }

        float s0 = waveReduceSum(s0a + s0b + s0c + s0d);
        float s1 = waveReduceSum(s1a + s1b);
        if (lane == 0) { sm0[wave] = s0; sm1[wave] = s1; }
        __syncthreads();
        if (threadIdx.x == 0) {
            ws[rb]      = sm0[0] + sm0[1] + sm0[2] + sm0[3];
            ws[BR + rb] = sm1[0] + sm1[1] + sm1[2] + sm1[3];
        }
    }
}

__global__ void finalize_kernel(const float* __restrict__ ws,
                                const float* __restrict__ lamb,
                                float* __restrict__ out)
{
    float a0 = 0.f, a1 = 0.f, a2 = 0.f;
    for (int i = threadIdx.x; i < BR; i += TPB) {
        a0 += ws[i];
        a1 += ws[BR + i];
    }
    for (int i = threadIdx.x; i < BP; i += TPB)
        a2 += ws[2 * BR + i];

    a0 = waveReduceSum(a0);
    a1 = waveReduceSum(a1);
    a2 = waveReduceSum(a2);

    __shared__ float m0[4], m1[4], m2[4];
    int wave = threadIdx.x >> 6;
    int lane = threadIdx.x & 63;
    if (lane == 0) { m0[wave] = a0; m1[wave] = a1; m2[wave] = a2; }
    __syncthreads();
    if (threadIdx.x == 0) {
        float A0 = m0[0] + m0[1] + m0[2] + m0[3];
        float A1 = m1[0] + m1[1] + m1[2] + m1[3];
        float A2 = m2[0] + m2[1] + m2[2] + m2[3];
        out[0] = sqrtf(A0) + lamb[0] * (sqrtf(A1) + A2);
    }
}

extern "C" void kernel_launch(void* const* d_in, const int* in_sizes, int n_in,
                              void* d_out, int out_size, void* d_ws, size_t ws_size,
                              hipStream_t stream) {
    const float* actual = (const float*)d_in[0];
    const float* pred   = (const float*)d_in[1];
    const float* lamb   = (const float*)d_in[2];
    const float* Pm     = (const float*)d_in[3];
    const float* S      = (const float*)d_in[4];
    const int*   ii     = (const int*)d_in[5];
    const int*   jj     = (const int*)d_in[6];
    float* out = (float*)d_out;
    float* ws  = (float*)d_ws;

    long nAP   = in_sizes[0];                       // 4096*4096
    long nP    = in_sizes[3];                       // 2048*2048
    int  K     = (int)lround(sqrt((double)nP));     // 2048
    int  Npair = in_sizes[5];                       // 128
    int  D     = (int)(in_sizes[4] / K);            // 1024

    fused_kernel<<<BP + BR, TPB, 0, stream>>>(actual, pred, Pm, S, ii, jj, ws,
                                              nAP, nP, Npair, D, K);
    finalize_kernel<<<1, TPB, 0, stream>>>(ws, lamb, out);
}

// Round 11
// 32.487 us; speedup vs baseline: 1.1592x; 1.1016x over previous
//
#include <hip/hip_runtime.h>
#include <math.h>

#define PBN 512    // pair blocks
#define RBN 512    // reducer blocks  (total 1024 = 4/CU at launch_bounds(256,4), all resident)
#define TPB 256

__device__ __forceinline__ float waveReduceSum(float v) {
    #pragma unroll
    for (int off = 32; off > 0; off >>= 1)
        v += __shfl_down(v, off, 64);
    return v;
}

#define CONS(AV, PV, S) { float d_;                       \
    d_ = (AV).x - (PV).x; S += d_ * d_;                   \
    d_ = (AV).y - (PV).y; S += d_ * d_;                   \
    d_ = (AV).z - (PV).z; S += d_ * d_;                   \
    d_ = (AV).w - (PV).w; S += d_ * d_; }

#define RCONS(V, S) { float r_;                           \
    r_ = fmaxf((V).x, 0.f); S += r_ * r_;                 \
    r_ = fmaxf((V).y, 0.f); S += r_ * r_;                 \
    r_ = fmaxf((V).z, 0.f); S += r_ * r_;                 \
    r_ = fmaxf((V).w, 0.f); S += r_ * r_; }

// ws layout (floats): [0,RBN) s0 partials ; [RBN,2RBN) s1 partials ; [2RBN,2RBN+PBN) pair partials
__global__ __launch_bounds__(TPB, 4)
void fused_kernel(const float* __restrict__ a,
                  const float* __restrict__ p,
                  const float* __restrict__ Pm,
                  const float* __restrict__ S,
                  const int* __restrict__ ii,
                  const int* __restrict__ jj,
                  float* __restrict__ ws,
                  long nAP, long nP, int Npair, int D, int K)
{
    __shared__ float sm0[4], sm1[4];
    const int wave = threadIdx.x >> 6;
    const int lane = threadIdx.x & 63;
    const int bid  = blockIdx.x;

    if (bid < PBN) {
        // ---- pair role: 32 pairs/block, 8/wave, Si hoisted (8 | Npair=128) ----
        const int totalPairs = Npair * Npair;
        const int base = bid * 32 + wave * 8;
        float local = 0.f;

        if (D == 1024 && base + 7 < totalPairs && (base % Npair) + 7 < Npair) {
            const int ig = base / Npair;
            const int j0 = base - ig * Npair;
            const int ri = ii[ig];
            const float4* Si4 = (const float4*)(S + (long)ri * D);
            float4 x0 = Si4[lane];
            float4 x1 = Si4[lane + 64];
            float4 x2 = Si4[lane + 128];
            float4 x3 = Si4[lane + 192];
            const long riK = (long)ri * K;

            float d2q[8];
            int   rjq[8];
            #pragma unroll
            for (int q = 0; q < 8; ++q) {
                const int rj = jj[j0 + q];
                rjq[q] = rj;
                const float4* Sj4 = (const float4*)(S + (long)rj * D);
                float4 y0 = Sj4[lane];
                float4 y1 = Sj4[lane + 64];
                float4 y2 = Sj4[lane + 128];
                float4 y3 = Sj4[lane + 192];
                float d2 = 0.f, e;
                e = x0.x - y0.x; d2 += e * e;
                e = x0.y - y0.y; d2 += e * e;
                e = x0.z - y0.z; d2 += e * e;
                e = x0.w - y0.w; d2 += e * e;
                e = x1.x - y1.x; d2 += e * e;
                e = x1.y - y1.y; d2 += e * e;
                e = x1.z - y1.z; d2 += e * e;
                e = x1.w - y1.w; d2 += e * e;
                e = x2.x - y2.x; d2 += e * e;
                e = x2.y - y2.y; d2 += e * e;
                e = x2.z - y2.z; d2 += e * e;
                e = x2.w - y2.w; d2 += e * e;
                e = x3.x - y3.x; d2 += e * e;
                e = x3.y - y3.y; d2 += e * e;
                e = x3.z - y3.z; d2 += e * e;
                e = x3.w - y3.w; d2 += e * e;
                d2q[q] = d2;
            }
            #pragma unroll
            for (int q = 0; q < 8; ++q)
                d2q[q] = waveReduceSum(d2q[q]);
            if (lane == 0) {
                #pragma unroll
                for (int q = 0; q < 8; ++q)
                    if (d2q[q] > 0.f)
                        local += fmaxf(Pm[riK + rjq[q]], 0.f) * sqrtf(d2q[q]);
            }
        } else {
            // generic fallback
            for (int q = 0; q < 8; ++q) {
                int pair = base + q;
                if (pair < totalPairs) {
                    int ig = pair / Npair;
                    int j  = pair - ig * Npair;
                    int ri = ii[ig];
                    int rj = jj[j];
                    const float* Si = S + (long)ri * D;
                    const float* Sj = S + (long)rj * D;
                    float d2 = 0.f;
                    for (int c = lane; c < D; c += 64) {
                        float e = Si[c] - Sj[c];
                        d2 += e * e;
                    }
                    d2 = waveReduceSum(d2);
                    if (lane == 0 && d2 > 0.f)
                        local += fmaxf(Pm[(long)ri * K + rj], 0.f) * sqrtf(d2);
                }
            }
        }
        if (lane == 0) sm0[wave] = local;
        __syncthreads();
        if (threadIdx.x == 0)
            ws[2 * RBN + bid] = sm0[0] + sm0[1] + sm0[2] + sm0[3];
    } else {
        // ---- reducer role: software-pipelined double-buffered stream ----
        const int  rb     = bid - PBN;
        const long tid    = (long)rb * TPB + threadIdx.x;
        const long stride = (long)RBN * TPB;          // 131,072 threads

        const float4* a4 = (const float4*)a;
        const float4* p4 = (const float4*)p;
        const long n4  = nAP >> 2;                    // 4,194,304 -> 32/thread = 8 batches of 4
        const long nP4 = nP  >> 2;                    // 1,048,576 -> 8/thread  = 2 batches of 4

        float s0a = 0.f, s0b = 0.f, s0c = 0.f, s0d = 0.f;

        if (n4 == 32L * stride) {
            float4 A[2][4], Pv[2][4];
            long i = tid;
            #pragma unroll
            for (int u = 0; u < 4; ++u) {
                A[0][u]  = a4[i + u * stride];
                Pv[0][u] = p4[i + u * stride];
            }
            i += 4 * stride;
            #pragma unroll
            for (int it = 1; it < 8; ++it) {          // fully unrolled: all indices constant
                const int nxt = it & 1;
                const int cur = nxt ^ 1;
                #pragma unroll
                for (int u = 0; u < 4; ++u) {
                    A[nxt][u]  = a4[i + u * stride];
                    Pv[nxt][u] = p4[i + u * stride];
                }
                i += 4 * stride;
                __builtin_amdgcn_sched_barrier(0);    // prefetch stays above consume
                CONS(A[cur][0], Pv[cur][0], s0a);
                CONS(A[cur][1], Pv[cur][1], s0b);
                CONS(A[cur][2], Pv[cur][2], s0c);
                CONS(A[cur][3], Pv[cur][3], s0d);
            }
            CONS(A[1][0], Pv[1][0], s0a);             // batch 7 lives in buffer 1
            CONS(A[1][1], Pv[1][1], s0b);
            CONS(A[1][2], Pv[1][2], s0c);
            CONS(A[1][3], Pv[1][3], s0d);
        } else {
            for (long i = tid; i < n4; i += stride) {
                float4 av = a4[i], pv = p4[i];
                CONS(av, pv, s0a);
            }
        }

        const float4* P4 = (const float4*)Pm;
        float s1a = 0.f, s1b = 0.f;
        if (nP4 == 8L * stride) {
            float4 B[2][4];
            long q = tid;
            #pragma unroll
            for (int u = 0; u < 4; ++u) B[0][u] = P4[q + u * stride];
            q += 4 * stride;
            #pragma unroll
            for (int u = 0; u < 4; ++u) B[1][u] = P4[q + u * stride];
            __builtin_amdgcn_sched_barrier(0);
            RCONS(B[0][0], s1a); RCONS(B[0][1], s1b);
            RCONS(B[0][2], s1a); RCONS(B[0][3], s1b);
            RCONS(B[1][0], s1a); RCONS(B[1][1], s1b);
            RCONS(B[1][2], s1a); RCONS(B[1][3], s1b);
        } else {
            for (long q = tid; q < nP4; q += stride) {
                float4 v = P4[q];
                RCONS(v, s1a);
            }
        }

        float s0 = waveReduceSum(s0a + s0b + s0c + s0d);
        float s1 = waveReduceSum(s1a + s1b);
        if (lane == 0) { sm0[wave] = s0; sm1[wave] = s1; }
        __syncthreads();
        if (threadIdx.x == 0) {
            ws[rb]       = sm0[0] + sm0[1] + sm0[2] + sm0[3];
            ws[RBN + rb] = sm1[0] + sm1[1] + sm1[2] + sm1[3];
        }
    }
}

__global__ void finalize_kernel(const float* __restrict__ ws,
                                const float* __restrict__ lamb,
                                float* __restrict__ out)
{
    float a0 = 0.f, a1 = 0.f, a2 = 0.f;
    for (int i = threadIdx.x; i < RBN; i += TPB) {
        a0 += ws[i];
        a1 += ws[RBN + i];
    }
    for (int i = threadIdx.x; i < PBN; i += TPB)
        a2 += ws[2 * RBN + i];

    a0 = waveReduceSum(a0);
    a1 = waveReduceSum(a1);
    a2 = waveReduceSum(a2);

    __shared__ float m0[4], m1[4], m2[4];
    int wave = threadIdx.x >> 6;
    int lane = threadIdx.x & 63;
    if (lane == 0) { m0[wave] = a0; m1[wave] = a1; m2[wave] = a2; }
    __syncthreads();
    if (threadIdx.x == 0) {
        float A0 = m0[0] + m0[1] + m0[2] + m0[3];
        float A1 = m1[0] + m1[1] + m1[2] + m1[3];
        float A2 = m2[0] + m2[1] + m2[2] + m2[3];
        out[0] = sqrtf(A0) + lamb[0] * (sqrtf(A1) + A2);
    }
}

extern "C" void kernel_launch(void* const* d_in, const int* in_sizes, int n_in,
                              void* d_out, int out_size, void* d_ws, size_t ws_size,
                              hipStream_t stream) {
    const float* actual = (const float*)d_in[0];
    const float* pred   = (const float*)d_in[1];
    const float* lamb   = (const float*)d_in[2];
    const float* Pm     = (const float*)d_in[3];
    const float* S      = (const float*)d_in[4];
    const int*   ii     = (const int*)d_in[5];
    const int*   jj     = (const int*)d_in[6];
    float* out = (float*)d_out;
    float* ws  = (float*)d_ws;

    long nAP   = in_sizes[0];                       // 4096*4096
    long nP    = in_sizes[3];                       // 2048*2048
    int  K     = (int)lround(sqrt((double)nP));     // 2048
    int  Npair = in_sizes[5];                       // 128
    int  D     = (int)(in_sizes[4] / K);            // 1024

    fused_kernel<<<PBN + RBN, TPB, 0, stream>>>(actual, pred, Pm, S, ii, jj, ws,
                                                nAP, nP, Npair, D, K);
    finalize_kernel<<<1, TPB, 0, stream>>>(ws, lamb, out);
}